// Round 2
// 1633.550 us; speedup vs baseline: 1.4552x; 1.4552x over previous
//
#include <hip/hip_runtime.h>
#include <math.h>

#define TT 35
#define BB 64
#define EMB 1500
#define HID 1500
#define VOCAB 10000
#define KT 3072          // EMB+HID padded to x128 (4 k-groups x 24 chunks x 32)
#define KG 768           // K per k-group
#define NCH 24           // chunks of 32 per k-group
#define KLP 1504         // HID padded to x32 (logits K)
#define NBLK 157         // vocab n-blocks of 64
#define MBLK 35          // 2240/64 row blocks
#define LBLK 94          // column-blocks per LSTM layer (1504/16)
#define FORGET_BIAS 1.0f

typedef __bf16 bf16x8 __attribute__((ext_vector_type(8)));
typedef float f32x4 __attribute__((ext_vector_type(4)));

__device__ __forceinline__ unsigned short f2bf(float f) {
    unsigned int u = __builtin_bit_cast(unsigned int, f);
    u += 0x7fffu + ((u >> 16) & 1u);           // RNE
    return (unsigned short)(u >> 16);
}
__device__ __forceinline__ float sigmoidf_(float x) { return 1.0f / (1.0f + expf(-x)); }

#define GLOAD_LDS16(gp, lp) __builtin_amdgcn_global_load_lds( \
    (const __attribute__((address_space(1))) void*)(gp),      \
    (__attribute__((address_space(3))) void*)(lp), 16, 0, 0)

// ---- W (K x N fp32) -> WT (N x KP bf16), zero-fill k in [K,KP) ----
__global__ __launch_bounds__(256) void convT(const float* __restrict__ W,
                                             unsigned short* __restrict__ WT,
                                             int K, int N, int KP) {
    __shared__ float tile[32][33];
    int tx = threadIdx.x, ty = threadIdx.y;    // 32 x 8
    int n0 = blockIdx.x * 32, k0 = blockIdx.y * 32;
#pragma unroll
    for (int i = 0; i < 4; ++i) {
        int k = k0 + ty + 8 * i, n = n0 + tx;
        tile[ty + 8 * i][tx] = (k < K && n < N) ? W[(size_t)k * N + n] : 0.f;
    }
    __syncthreads();
#pragma unroll
    for (int i = 0; i < 4; ++i) {
        int n = n0 + ty + 8 * i, k = k0 + tx;
        if (n < N) WT[(size_t)n * KP + k] = f2bf(tile[tx][ty + 8 * i]);
    }
}

// ---- embedding gather -> bf16 into per-step A0 buffers (cols 0..1499) ----
__global__ __launch_bounds__(256) void embed_kernel(const int* __restrict__ x,
                                                    const float* __restrict__ emb,
                                                    unsigned short* __restrict__ A0) {
    int tok = blockIdx.x;                       // t*BB + b (t-major)
    int v = x[tok];
    const float* src = emb + (size_t)v * EMB;
    unsigned short* dst = A0 + (size_t)tok * KT;
    for (int i = threadIdx.x; i < EMB; i += 256) dst[i] = f2bf(src[i]);
}

// ---- fused LSTM pair step: software pipeline layer0[k] (blocks 0..93) with
// ---- layer1[k-1] (blocks 94..187). The two are independent: both consume only
// ---- state written by launch k-1. Same inner body as the proven lstm_fused.
// block 1024 = 16 waves: kg = wv>>2 (k-group), mt = wv&3 (m-tile)
// Per chunk (BK=32): each kg stages A-tile 64x32 + B-tile 64x32 (4KB each) double-buffered.
// LDS: stage [buf][ab][kg] 4KB each = 64KB exactly; epilogue reduction overlays it.
__global__ __launch_bounds__(1024) void lstm_pair(
        const unsigned short* __restrict__ A_0, const unsigned short* __restrict__ WT_0,
        const float* __restrict__ bias_0, float* __restrict__ cst_0,
        unsigned short* __restrict__ d1_0, int s1_0, unsigned short* __restrict__ d2_0, int s2_0,
        const unsigned short* __restrict__ A_1, const unsigned short* __restrict__ WT_1,
        const float* __restrict__ bias_1, float* __restrict__ cst_1,
        unsigned short* __restrict__ d1_1, int s1_1, unsigned short* __restrict__ d2_1, int s2_1) {
    __shared__ __align__(16) unsigned char smem[65536];

    const unsigned short* A;  const unsigned short* WT;
    const float* bias;        float* cst;
    unsigned short* d1; int s1; unsigned short* d2; int s2;
    int nb;
    if (blockIdx.x < LBLK) {
        if (!A_0) return;
        A = A_0; WT = WT_0; bias = bias_0; cst = cst_0;
        d1 = d1_0; s1 = s1_0; d2 = d2_0; s2 = s2_0;
        nb = blockIdx.x;
    } else {
        if (!A_1) return;
        A = A_1; WT = WT_1; bias = bias_1; cst = cst_1;
        d1 = d1_1; s1 = s1_1; d2 = d2_1; s2 = s2_1;
        nb = blockIdx.x - LBLK;
    }

    int tid = threadIdx.x;
    int wv = tid >> 6, lane = tid & 63;
    int mt = wv & 3, kg = wv >> 2;
    int quad = lane >> 4, l16 = lane & 15;
    int col = nb * 16 + l16;

    // ---- staging setup: this wave issues instrs q0=2mt, q1=2mt+1 for its kg ----
    int rr = lane >> 2, p = lane & 3;
    int sp = p ^ (rr & 3);                      // XOR swizzle on the GLOBAL side
    int kbase = kg * KG;
    int q0 = mt * 2, q1 = q0 + 1;
    const unsigned short* gp[2];
    int ldsoff[2];
#pragma unroll
    for (int ii = 0; ii < 2; ++ii) {
        int q = ii ? q1 : q0;
        if (q < 4) {                            // A rows 16q+rr
            gp[ii] = A + (size_t)(16 * q + rr) * KT + kbase + sp * 8;
        } else {                                // B: gate g=q-4, col index rr
            int g = q - 4;
            int ci = nb * 16 + rr; if (ci > HID - 1) ci = HID - 1;   // clamp pad cols
            gp[ii] = WT + (size_t)(g * HID + ci) * KT + kbase + sp * 8;
        }
        ldsoff[ii] = ((q >> 2) * 4 + kg) * 4096 + (q & 3) * 1024;    // + buf*32768
    }

    int swz = (quad ^ (l16 & 3)) * 16;
    int aoff = (0 * 4 + kg) * 4096 + (mt * 16 + l16) * 64 + swz;     // + buf*32768
    int boff = (1 * 4 + kg) * 4096 + l16 * 64 + swz;                 // + gate*1024 + buf*32768

    f32x4 acc0 = {0.f,0.f,0.f,0.f}, acc1 = acc0, acc2 = acc0, acc3 = acc0;

    // prologue: stage chunk 0 into buf 0
    GLOAD_LDS16(gp[0], smem + ldsoff[0]);
    GLOAD_LDS16(gp[1], smem + ldsoff[1]);
    __syncthreads();

    for (int c = 0; c < NCH; ++c) {
        int buf = c & 1;
        if (c + 1 < NCH) {                      // stage next chunk into other buffer
            int nb2 = (buf ^ 1) * 32768;
            GLOAD_LDS16(gp[0] + (c + 1) * 32, smem + nb2 + ldsoff[0]);
            GLOAD_LDS16(gp[1] + (c + 1) * 32, smem + nb2 + ldsoff[1]);
        }
        const unsigned char* base = smem + buf * 32768;
        bf16x8 a  = *(const bf16x8*)(base + aoff);
        bf16x8 b0 = *(const bf16x8*)(base + boff);
        bf16x8 b1 = *(const bf16x8*)(base + boff + 1024);
        bf16x8 b2 = *(const bf16x8*)(base + boff + 2048);
        bf16x8 b3 = *(const bf16x8*)(base + boff + 3072);
        acc0 = __builtin_amdgcn_mfma_f32_16x16x32_bf16(a, b0, acc0, 0, 0, 0);
        acc1 = __builtin_amdgcn_mfma_f32_16x16x32_bf16(a, b1, acc1, 0, 0, 0);
        acc2 = __builtin_amdgcn_mfma_f32_16x16x32_bf16(a, b2, acc2, 0, 0, 0);
        acc3 = __builtin_amdgcn_mfma_f32_16x16x32_bf16(a, b3, acc3, 0, 0, 0);
        __syncthreads();                        // drains stage(c+1); protects buf reuse
    }

    // ---- epilogue: k-group reduction through LDS (overlays stage memory) ----
    float* red = (float*)smem;                  // [12 waves][64 lanes][16]
    if (kg > 0) {
        int w = (kg - 1) * 4 + mt;
#pragma unroll
        for (int r = 0; r < 4; ++r) {
            red[(w * 64 + lane) * 16 + r]      = acc0[r];
            red[(w * 64 + lane) * 16 + 4 + r]  = acc1[r];
            red[(w * 64 + lane) * 16 + 8 + r]  = acc2[r];
            red[(w * 64 + lane) * 16 + 12 + r] = acc3[r];
        }
    }
    __syncthreads();
    if (kg == 0) {
#pragma unroll
        for (int k2 = 0; k2 < 3; ++k2) {
            int w = k2 * 4 + mt;
#pragma unroll
            for (int r = 0; r < 4; ++r) {
                acc0[r] += red[(w * 64 + lane) * 16 + r];
                acc1[r] += red[(w * 64 + lane) * 16 + 4 + r];
                acc2[r] += red[(w * 64 + lane) * 16 + 8 + r];
                acc3[r] += red[(w * 64 + lane) * 16 + 12 + r];
            }
        }
        if (col < HID) {
            float bi = bias[col], bj = bias[HID + col];
            float bf_ = bias[2 * HID + col], bo = bias[3 * HID + col];
#pragma unroll
            for (int r = 0; r < 4; ++r) {
                int row = mt * 16 + quad * 4 + r;
                float zi = acc0[r] + bi;
                float zj = acc1[r] + bj;
                float zf = acc2[r] + bf_;
                float zo = acc3[r] + bo;
                int ci = row * HID + col;
                float cn = cst[ci] * sigmoidf_(zf + FORGET_BIAS) + sigmoidf_(zi) * tanhf(zj);
                float hn = tanhf(cn) * sigmoidf_(zo);
                cst[ci] = cn;
                unsigned short hb = f2bf(hn);
                d1[(size_t)row * s1 + col] = hb;
                if (d2) d2[(size_t)row * s2 + col] = hb;
            }
        }
    }
}

// ---- logits + flash fold: grid (MBLK, NBLK); block 256 = 4 waves x 16 rows ----
// XCD-chunked bijective swizzle (m204): consecutive blocks on one XCD share the
// same WT column-slice -> WT fills one L2 instead of 8.
__global__ __launch_bounds__(256) void logits_fold(const unsigned short* __restrict__ A,   // 2240 x KLP
                                                   const unsigned short* __restrict__ WT,  // 10000 x KLP
                                                   const float* __restrict__ sb,
                                                   const int* __restrict__ y,
                                                   float2* __restrict__ partials,          // [2240][NBLK]
                                                   float* __restrict__ tgtlog) {           // [2240]
    const int NWG = MBLK * NBLK;                // 5495
    const int NX = 8;
    const int q = NWG / NX, r = NWG % NX;       // 686, 7
    int orig = blockIdx.x + MBLK * blockIdx.y;  // dispatch-linear id (m fastest)
    int xcd = orig % NX, idx = orig / NX;
    int wgid = (xcd < r ? xcd * (q + 1) : r * (q + 1) + (xcd - r) * q) + idx;
    int mb = wgid % MBLK, nb = wgid / MBLK;

    int tid = threadIdx.x;
    int wv = tid >> 6, lane = tid & 63;
    int quad = lane >> 4, l16 = lane & 15;
    int row0 = mb * 64 + wv * 16;
    int n0 = nb * 64;
    f32x4 acc[4];
#pragma unroll
    for (int s = 0; s < 4; ++s) acc[s] = (f32x4){0.f, 0.f, 0.f, 0.f};
    const unsigned short* ap = A + (size_t)(row0 + l16) * KLP + quad * 8;
    const unsigned short* bp[4];
    int colv[4]; float bs[4];
#pragma unroll
    for (int s = 0; s < 4; ++s) {
        int c = n0 + s * 16 + l16;
        colv[s] = c;
        int cc = (c < VOCAB) ? c : (VOCAB - 1);
        bp[s] = WT + (size_t)cc * KLP + quad * 8;
        bs[s] = sb[cc];
    }
    for (int it = 0; it < KLP / 32; ++it) {
        bf16x8 a  = *(const bf16x8*)ap;
        bf16x8 b0 = *(const bf16x8*)bp[0];
        bf16x8 b1 = *(const bf16x8*)bp[1];
        bf16x8 b2 = *(const bf16x8*)bp[2];
        bf16x8 b3 = *(const bf16x8*)bp[3];
        acc[0] = __builtin_amdgcn_mfma_f32_16x16x32_bf16(a, b0, acc[0], 0, 0, 0);
        acc[1] = __builtin_amdgcn_mfma_f32_16x16x32_bf16(a, b1, acc[1], 0, 0, 0);
        acc[2] = __builtin_amdgcn_mfma_f32_16x16x32_bf16(a, b2, acc[2], 0, 0, 0);
        acc[3] = __builtin_amdgcn_mfma_f32_16x16x32_bf16(a, b3, acc[3], 0, 0, 0);
        ap += 32; bp[0] += 32; bp[1] += 32; bp[2] += 32; bp[3] += 32;
    }
#pragma unroll
    for (int r2 = 0; r2 < 4; ++r2) {
        float v0 = acc[0][r2] + bs[0];
        float v1 = acc[1][r2] + bs[1];
        float v2 = acc[2][r2] + bs[2];
        float v3 = acc[3][r2] + bs[3];
        if (colv[0] >= VOCAB) v0 = -1e30f;
        if (colv[1] >= VOCAB) v1 = -1e30f;
        if (colv[2] >= VOCAB) v2 = -1e30f;
        if (colv[3] >= VOCAB) v3 = -1e30f;
        int row = row0 + quad * 4 + r2;
        int t = y[row];
        float tv = -1e30f;
        if (colv[0] == t) tv = v0;
        if (colv[1] == t) tv = v1;
        if (colv[2] == t) tv = v2;
        if (colv[3] == t) tv = v3;
        float mx = fmaxf(fmaxf(v0, v1), fmaxf(v2, v3));
#pragma unroll
        for (int d = 1; d < 16; d <<= 1) mx = fmaxf(mx, __shfl_xor(mx, d, 64));
        float sum = expf(v0 - mx) + expf(v1 - mx) + expf(v2 - mx) + expf(v3 - mx);
#pragma unroll
        for (int d = 1; d < 16; d <<= 1) sum += __shfl_xor(sum, d, 64);
#pragma unroll
        for (int d = 1; d < 16; d <<= 1) tv = fmaxf(tv, __shfl_xor(tv, d, 64));
        if (l16 == 0) {
            partials[(size_t)row * NBLK + nb] = make_float2(mx, sum);
            if (tv > -5e29f) tgtlog[row] = tv;
        }
    }
}

// ---- combine per-block partials -> nll per row; one wave per row ----
__global__ __launch_bounds__(64) void nll_reduce(const float2* __restrict__ partials,
                                                 const float* __restrict__ tgtlog,
                                                 float* __restrict__ nll) {
    int row = blockIdx.x;
    int lane = threadIdx.x;
    float2 loc[3];
    int cnt = 0;
    float m = -1e30f;
    for (int i = lane; i < NBLK; i += 64) {
        float2 p = partials[(size_t)row * NBLK + i];
        loc[cnt++] = p;
        m = fmaxf(m, p.x);
    }
#pragma unroll
    for (int d = 1; d < 64; d <<= 1) m = fmaxf(m, __shfl_xor(m, d, 64));
    float s = 0.f;
    for (int j = 0; j < cnt; ++j) s += loc[j].y * expf(loc[j].x - m);
#pragma unroll
    for (int d = 1; d < 64; d <<= 1) s += __shfl_xor(s, d, 64);
    if (lane == 0) nll[row] = -(tgtlog[row] - m - logf(s));
}

__global__ __launch_bounds__(256) void loss_kernel(const float* __restrict__ nll,
                                                   float* __restrict__ out) {
    __shared__ float red[256];
    int tid = threadIdx.x;
    float s = 0.f;
    for (int i = tid; i < TT * BB; i += 256) s += nll[i];
    red[tid] = s; __syncthreads();
    for (int st = 128; st > 0; st >>= 1) { if (tid < st) red[tid] += red[tid + st]; __syncthreads(); }
    if (tid == 0) out[0] = red[0] / (float)BB;
}

extern "C" void kernel_launch(void* const* d_in, const int* in_sizes, int n_in,
                              void* d_out, int out_size, void* d_ws, size_t ws_size,
                              hipStream_t stream) {
    const int*   x   = (const int*)d_in[0];
    const int*   y   = (const int*)d_in[1];
    const float* emb = (const float*)d_in[2];
    const float* W0  = (const float*)d_in[3];
    const float* b0  = (const float*)d_in[4];
    const float* W1  = (const float*)d_in[5];
    const float* b1  = (const float*)d_in[6];
    const float* sw  = (const float*)d_in[7];
    const float* sb  = (const float*)d_in[8];
    float* out = (float*)d_out;

    // ---- workspace layout; total ~129 MB ----
    char* p = (char*)d_ws;
    unsigned short* A0   = (unsigned short*)p; p += (size_t)TT * BB * KT * 2;   // 13,762,560
    unsigned short* A1   = (unsigned short*)p; p += (size_t)2 * BB * KT * 2;    //    786,432
    unsigned short* outs = (unsigned short*)p; p += (size_t)TT * BB * KLP * 2;  //  6,737,920
    float* c0 = (float*)p; p += (size_t)BB * HID * 4;
    float* c1 = (float*)p; p += (size_t)BB * HID * 4;
    size_t zero_bytes = (size_t)(p - (char*)d_ws);                              // 22,054,912
    unsigned short* WbT0 = (unsigned short*)p; p += (size_t)6000 * KT * 2;      // 36,864,000
    unsigned short* WbT1 = (unsigned short*)p; p += (size_t)6000 * KT * 2;      // 36,864,000
    unsigned short* swT  = (unsigned short*)p; p += (size_t)VOCAB * KLP * 2;    // 30,080,000
    float2* partials = (float2*)p; p += (size_t)TT * BB * NBLK * 8;             //  2,813,440
    float* tgtlog = (float*)p; p += (size_t)TT * BB * 4;
    float* nll    = (float*)p;

    hipMemsetAsync(d_ws, 0, zero_bytes, stream);

    dim3 cblk(32, 8);
    convT<<<dim3(188, 96), cblk, 0, stream>>>(W0, WbT0, 3000, 6000, KT);
    convT<<<dim3(188, 96), cblk, 0, stream>>>(W1, WbT1, 3000, 6000, KT);
    convT<<<dim3(313, 47), cblk, 0, stream>>>(sw, swT, HID, VOCAB, KLP);

    embed_kernel<<<TT * BB, 256, 0, stream>>>(x, emb, A0);

    // software pipeline: launch k runs layer0[k] (blocks 0..93) and layer1[k-1]
    // (blocks 94..187) concurrently. 36 launches instead of 70, 188 CUs busy.
    for (int k = 0; k <= TT; ++k) {
        const unsigned short* A0t = (k < TT) ? A0 + (size_t)k * BB * KT : nullptr;
        unsigned short* d1_0 = A1 + (size_t)(k & 1) * BB * KT;
        unsigned short* d2_0 = (k < TT - 1) ? (A0 + (size_t)(k + 1) * BB * KT + EMB) : nullptr;

        const unsigned short* A1t = (k >= 1) ? A1 + (size_t)((k - 1) & 1) * BB * KT : nullptr;
        unsigned short* d1_1 = A1 + (size_t)(k & 1) * BB * KT + HID;
        unsigned short* d2_1 = (k >= 1) ? outs + (size_t)(k - 1) * BB * KLP : nullptr;

        lstm_pair<<<188, 1024, 0, stream>>>(A0t, WbT0, b0, c0, d1_0, KT, d2_0, KT,
                                            A1t, WbT1, b1, c1, d1_1, KT, d2_1, KLP);
    }

    logits_fold<<<dim3(MBLK, NBLK), 256, 0, stream>>>(outs, swT, sb, y, partials, tgtlog);
    nll_reduce<<<TT * BB, 64, 0, stream>>>(partials, tgtlog, nll);
    loss_kernel<<<1, 256, 0, stream>>>(nll, out);
}

// Round 3
// 1378.170 us; speedup vs baseline: 1.7249x; 1.1853x over previous
//
#include <hip/hip_runtime.h>
#include <math.h>

#define TT 35
#define BB 64
#define EMB 1500
#define HID 1500
#define VOCAB 10000
#define KT 3072          // EMB+HID padded to x128 (4 k-groups x 24 chunks x 32)
#define KG 768           // K per k-group
#define NCH 24           // chunks of 32 per k-group
#define KLP 1504         // HID padded to x32 (logits K)
#define NBLK 158         // vocab 64-col blocks (79 tiles x 2 halves)
#define MROWS 2240       // T*B rows
#define MPAD 2304        // padded to 18*128
#define LBLK 94          // column-blocks per LSTM layer
#define FORGET_BIAS 1.0f

typedef __bf16 bf16x8 __attribute__((ext_vector_type(8)));
typedef float f32x4 __attribute__((ext_vector_type(4)));

__device__ __forceinline__ unsigned short f2bf(float f) {
    unsigned int u = __builtin_bit_cast(unsigned int, f);
    u += 0x7fffu + ((u >> 16) & 1u);           // RNE
    return (unsigned short)(u >> 16);
}
__device__ __forceinline__ float sigmoidf_(float x) { return 1.0f / (1.0f + expf(-x)); }

#define GLOAD_LDS16(gp, lp) __builtin_amdgcn_global_load_lds( \
    (const __attribute__((address_space(1))) void*)(gp),      \
    (__attribute__((address_space(3))) void*)(lp), 16, 0, 0)

// ---- W (K x N fp32) -> WT (N x KP bf16), zero-fill k in [K,KP) ----
__global__ __launch_bounds__(256) void convT(const float* __restrict__ W,
                                             unsigned short* __restrict__ WT,
                                             int K, int N, int KP) {
    __shared__ float tile[32][33];
    int tx = threadIdx.x, ty = threadIdx.y;    // 32 x 8
    int n0 = blockIdx.x * 32, k0 = blockIdx.y * 32;
#pragma unroll
    for (int i = 0; i < 4; ++i) {
        int k = k0 + ty + 8 * i, n = n0 + tx;
        tile[ty + 8 * i][tx] = (k < K && n < N) ? W[(size_t)k * N + n] : 0.f;
    }
    __syncthreads();
#pragma unroll
    for (int i = 0; i < 4; ++i) {
        int n = n0 + ty + 8 * i, k = k0 + tx;
        if (n < N) WT[(size_t)n * KP + k] = f2bf(tile[tx][ty + 8 * i]);
    }
}

// ---- embedding gather -> bf16 into per-step A0 buffers (cols 0..1499) ----
__global__ __launch_bounds__(256) void embed_kernel(const int* __restrict__ x,
                                                    const float* __restrict__ emb,
                                                    unsigned short* __restrict__ A0) {
    int tok = blockIdx.x;                       // t*BB + b (t-major)
    int v = x[tok];
    const float* src = emb + (size_t)v * EMB;
    unsigned short* dst = A0 + (size_t)tok * KT;
    for (int i = threadIdx.x; i < EMB; i += 256) dst[i] = f2bf(src[i]);
}

// ---- fused LSTM pair step: software pipeline layer0[k] (blocks 0..93) with
// ---- layer1[k-1] (blocks 94..187). Proven round-2 structure, unchanged.
__global__ __launch_bounds__(1024) void lstm_pair(
        const unsigned short* __restrict__ A_0, const unsigned short* __restrict__ WT_0,
        const float* __restrict__ bias_0, float* __restrict__ cst_0,
        unsigned short* __restrict__ d1_0, int s1_0, unsigned short* __restrict__ d2_0, int s2_0,
        const unsigned short* __restrict__ A_1, const unsigned short* __restrict__ WT_1,
        const float* __restrict__ bias_1, float* __restrict__ cst_1,
        unsigned short* __restrict__ d1_1, int s1_1, unsigned short* __restrict__ d2_1, int s2_1) {
    __shared__ __align__(16) unsigned char smem[65536];

    const unsigned short* A;  const unsigned short* WT;
    const float* bias;        float* cst;
    unsigned short* d1; int s1; unsigned short* d2; int s2;
    int nb;
    if (blockIdx.x < LBLK) {
        if (!A_0) return;
        A = A_0; WT = WT_0; bias = bias_0; cst = cst_0;
        d1 = d1_0; s1 = s1_0; d2 = d2_0; s2 = s2_0;
        nb = blockIdx.x;
    } else {
        if (!A_1) return;
        A = A_1; WT = WT_1; bias = bias_1; cst = cst_1;
        d1 = d1_1; s1 = s1_1; d2 = d2_1; s2 = s2_1;
        nb = blockIdx.x - LBLK;
    }

    int tid = threadIdx.x;
    int wv = tid >> 6, lane = tid & 63;
    int mt = wv & 3, kg = wv >> 2;
    int quad = lane >> 4, l16 = lane & 15;
    int col = nb * 16 + l16;

    int rr = lane >> 2, p = lane & 3;
    int sp = p ^ (rr & 3);                      // XOR swizzle on the GLOBAL side
    int kbase = kg * KG;
    int q0 = mt * 2, q1 = q0 + 1;
    const unsigned short* gp[2];
    int ldsoff[2];
#pragma unroll
    for (int ii = 0; ii < 2; ++ii) {
        int q = ii ? q1 : q0;
        if (q < 4) {                            // A rows 16q+rr
            gp[ii] = A + (size_t)(16 * q + rr) * KT + kbase + sp * 8;
        } else {                                // B: gate g=q-4, col index rr
            int g = q - 4;
            int ci = nb * 16 + rr; if (ci > HID - 1) ci = HID - 1;   // clamp pad cols
            gp[ii] = WT + (size_t)(g * HID + ci) * KT + kbase + sp * 8;
        }
        ldsoff[ii] = ((q >> 2) * 4 + kg) * 4096 + (q & 3) * 1024;    // + buf*32768
    }

    int swz = (quad ^ (l16 & 3)) * 16;
    int aoff = (0 * 4 + kg) * 4096 + (mt * 16 + l16) * 64 + swz;     // + buf*32768
    int boff = (1 * 4 + kg) * 4096 + l16 * 64 + swz;                 // + gate*1024 + buf*32768

    f32x4 acc0 = {0.f,0.f,0.f,0.f}, acc1 = acc0, acc2 = acc0, acc3 = acc0;

    GLOAD_LDS16(gp[0], smem + ldsoff[0]);
    GLOAD_LDS16(gp[1], smem + ldsoff[1]);
    __syncthreads();

    for (int c = 0; c < NCH; ++c) {
        int buf = c & 1;
        if (c + 1 < NCH) {
            int nb2 = (buf ^ 1) * 32768;
            GLOAD_LDS16(gp[0] + (c + 1) * 32, smem + nb2 + ldsoff[0]);
            GLOAD_LDS16(gp[1] + (c + 1) * 32, smem + nb2 + ldsoff[1]);
        }
        const unsigned char* base = smem + buf * 32768;
        bf16x8 a  = *(const bf16x8*)(base + aoff);
        bf16x8 b0 = *(const bf16x8*)(base + boff);
        bf16x8 b1 = *(const bf16x8*)(base + boff + 1024);
        bf16x8 b2 = *(const bf16x8*)(base + boff + 2048);
        bf16x8 b3 = *(const bf16x8*)(base + boff + 3072);
        acc0 = __builtin_amdgcn_mfma_f32_16x16x32_bf16(a, b0, acc0, 0, 0, 0);
        acc1 = __builtin_amdgcn_mfma_f32_16x16x32_bf16(a, b1, acc1, 0, 0, 0);
        acc2 = __builtin_amdgcn_mfma_f32_16x16x32_bf16(a, b2, acc2, 0, 0, 0);
        acc3 = __builtin_amdgcn_mfma_f32_16x16x32_bf16(a, b3, acc3, 0, 0, 0);
        __syncthreads();
    }

    float* red = (float*)smem;                  // [12 waves][64 lanes][16]
    if (kg > 0) {
        int w = (kg - 1) * 4 + mt;
#pragma unroll
        for (int r = 0; r < 4; ++r) {
            red[(w * 64 + lane) * 16 + r]      = acc0[r];
            red[(w * 64 + lane) * 16 + 4 + r]  = acc1[r];
            red[(w * 64 + lane) * 16 + 8 + r]  = acc2[r];
            red[(w * 64 + lane) * 16 + 12 + r] = acc3[r];
        }
    }
    __syncthreads();
    if (kg == 0) {
#pragma unroll
        for (int k2 = 0; k2 < 3; ++k2) {
            int w = k2 * 4 + mt;
#pragma unroll
            for (int r = 0; r < 4; ++r) {
                acc0[r] += red[(w * 64 + lane) * 16 + r];
                acc1[r] += red[(w * 64 + lane) * 16 + 4 + r];
                acc2[r] += red[(w * 64 + lane) * 16 + 8 + r];
                acc3[r] += red[(w * 64 + lane) * 16 + 12 + r];
            }
        }
        if (col < HID) {
            float bi = bias[col], bj = bias[HID + col];
            float bf_ = bias[2 * HID + col], bo = bias[3 * HID + col];
#pragma unroll
            for (int r = 0; r < 4; ++r) {
                int row = mt * 16 + quad * 4 + r;
                float zi = acc0[r] + bi;
                float zj = acc1[r] + bj;
                float zf = acc2[r] + bf_;
                float zo = acc3[r] + bo;
                int ci = row * HID + col;
                float cn = cst[ci] * sigmoidf_(zf + FORGET_BIAS) + sigmoidf_(zi) * tanhf(zj);
                float hn = tanhf(cn) * sigmoidf_(zo);
                cst[ci] = cn;
                unsigned short hb = f2bf(hn);
                d1[(size_t)row * s1 + col] = hb;
                if (d2) d2[(size_t)row * s2 + col] = hb;
            }
        }
    }
}

// ---- logits + flash fold, m97-style tiled GEMM ----
// 128x128 tile, BK=32, block 256 = 4 waves (wr=wv>>1 row-half, wc=wv&1 col-half),
// each wave 64x64 = 4x4 fragments. global_load_lds staging, double-buffered,
// XOR k-seg swizzle (pre-swizzled global source, swizzled ds_read). Fold epilogue
// per 64-col half (nb2 = bn*2 + wc), NBLK=158.
__global__ __launch_bounds__(256) void logits_fold(const unsigned short* __restrict__ A,   // MPAD x KLP
                                                   const unsigned short* __restrict__ WT,  // 10000 x KLP
                                                   const float* __restrict__ sb,
                                                   const int* __restrict__ y,
                                                   float2* __restrict__ partials,          // [2240][NBLK]
                                                   float* __restrict__ tgtlog) {           // [2240]
    __shared__ __align__(16) unsigned char smem[32768];   // [buf][A 8K | B 8K]

    // XCD-chunked bijective swizzle, n-fastest within chunk (A-panel L2-resident)
    const int NWG = 79 * 18;                    // 1422
    const int NX = 8;
    const int q = NWG / NX, r = NWG % NX;       // 177, 6
    int orig = blockIdx.x + 79 * blockIdx.y;
    int xcd = orig % NX, idx = orig / NX;
    int wgid = (xcd < r ? xcd * (q + 1) : r * (q + 1) + (xcd - r) * q) + idx;
    int bn = wgid % 79, mb = wgid / 79;
    int n0 = bn * 128;

    int tid = threadIdx.x;
    int wv = tid >> 6, lane = tid & 63;
    int wr = wv >> 1, wc = wv & 1;
    int quad = lane >> 4, l16 = lane & 15;

    // ---- staging: per wave 2 A-issues + 2 B-issues of 16 rows x 32k each ----
    int rr = lane >> 2;                         // row within 16
    int ks = (lane & 3) ^ (rr & 3);             // pre-swizzled k-seg on global side
    const unsigned short* gA[2]; const unsigned short* gB[2];
    int ldsA[2], ldsB[2];
#pragma unroll
    for (int i = 0; i < 2; ++i) {
        int r16 = wv * 2 + i;                   // 0..7
        int ra = mb * 128 + r16 * 16 + rr;      // A row (padded, < MPAD)
        gA[i] = A + (size_t)ra * KLP + ks * 8;
        ldsA[i] = r16 * 1024;
        int rb = n0 + r16 * 16 + rr;            // WT row
        if (rb > VOCAB - 1) rb = VOCAB - 1;     // clamp pad rows (masked later)
        gB[i] = WT + (size_t)rb * KLP + ks * 8;
        ldsB[i] = 8192 + r16 * 1024;
    }

    int sw16 = (quad ^ (l16 & 3)) * 16;
    int aoff[4], boff[4];
#pragma unroll
    for (int f = 0; f < 4; ++f) {
        aoff[f] = (wr * 64 + f * 16 + l16) * 64 + sw16;
        boff[f] = 8192 + (wc * 64 + f * 16 + l16) * 64 + sw16;
    }

    f32x4 acc[4][4];
#pragma unroll
    for (int i = 0; i < 4; ++i)
#pragma unroll
        for (int j = 0; j < 4; ++j) acc[i][j] = (f32x4){0.f, 0.f, 0.f, 0.f};

    // prologue: stage chunk 0 into buf 0
#pragma unroll
    for (int i = 0; i < 2; ++i) {
        GLOAD_LDS16(gA[i], smem + ldsA[i]);
        GLOAD_LDS16(gB[i], smem + ldsB[i]);
    }
    __syncthreads();

    for (int c = 0; c < KLP / 32; ++c) {
        int buf = c & 1;
        if (c + 1 < KLP / 32) {
            int ob = (buf ^ 1) * 16384;
#pragma unroll
            for (int i = 0; i < 2; ++i) {
                GLOAD_LDS16(gA[i] + (c + 1) * 32, smem + ob + ldsA[i]);
                GLOAD_LDS16(gB[i] + (c + 1) * 32, smem + ob + ldsB[i]);
            }
        }
        const unsigned char* base = smem + buf * 16384;
        bf16x8 a[4], b[4];
#pragma unroll
        for (int f = 0; f < 4; ++f) {
            a[f] = *(const bf16x8*)(base + aoff[f]);
            b[f] = *(const bf16x8*)(base + boff[f]);
        }
#pragma unroll
        for (int ar = 0; ar < 4; ++ar)
#pragma unroll
            for (int cb = 0; cb < 4; ++cb)
                acc[ar][cb] = __builtin_amdgcn_mfma_f32_16x16x32_bf16(a[ar], b[cb], acc[ar][cb], 0, 0, 0);
        __syncthreads();
    }

    // ---- fold epilogue: per 64-col half, same math as round-2 kernel ----
    int colv[4]; float bs[4];
#pragma unroll
    for (int cb = 0; cb < 4; ++cb) {
        int c = n0 + wc * 64 + cb * 16 + l16;
        colv[cb] = c;
        int cc = (c < VOCAB) ? c : (VOCAB - 1);
        bs[cb] = sb[cc];
    }
    int nb2 = bn * 2 + wc;
#pragma unroll
    for (int ar = 0; ar < 4; ++ar) {
#pragma unroll
        for (int r2 = 0; r2 < 4; ++r2) {
            float v0 = acc[ar][0][r2] + bs[0];
            float v1 = acc[ar][1][r2] + bs[1];
            float v2 = acc[ar][2][r2] + bs[2];
            float v3 = acc[ar][3][r2] + bs[3];
            if (colv[0] >= VOCAB) v0 = -1e30f;
            if (colv[1] >= VOCAB) v1 = -1e30f;
            if (colv[2] >= VOCAB) v2 = -1e30f;
            if (colv[3] >= VOCAB) v3 = -1e30f;
            int row = mb * 128 + wr * 64 + ar * 16 + quad * 4 + r2;
            int t = y[row < MROWS ? row : 0];
            float tv = -1e30f;
            if (colv[0] == t) tv = v0;
            if (colv[1] == t) tv = v1;
            if (colv[2] == t) tv = v2;
            if (colv[3] == t) tv = v3;
            float mx = fmaxf(fmaxf(v0, v1), fmaxf(v2, v3));
#pragma unroll
            for (int d = 1; d < 16; d <<= 1) mx = fmaxf(mx, __shfl_xor(mx, d, 64));
            float sum = expf(v0 - mx) + expf(v1 - mx) + expf(v2 - mx) + expf(v3 - mx);
#pragma unroll
            for (int d = 1; d < 16; d <<= 1) sum += __shfl_xor(sum, d, 64);
#pragma unroll
            for (int d = 1; d < 16; d <<= 1) tv = fmaxf(tv, __shfl_xor(tv, d, 64));
            if (l16 == 0 && row < MROWS) {
                partials[(size_t)row * NBLK + nb2] = make_float2(mx, sum);
                if (tv > -5e29f) tgtlog[row] = tv;
            }
        }
    }
}

// ---- combine per-block partials -> nll per row; one wave per row ----
__global__ __launch_bounds__(64) void nll_reduce(const float2* __restrict__ partials,
                                                 const float* __restrict__ tgtlog,
                                                 float* __restrict__ nll) {
    int row = blockIdx.x;
    int lane = threadIdx.x;
    float2 loc[3];
    int cnt = 0;
    float m = -1e30f;
    for (int i = lane; i < NBLK; i += 64) {
        float2 p = partials[(size_t)row * NBLK + i];
        loc[cnt++] = p;
        m = fmaxf(m, p.x);
    }
#pragma unroll
    for (int d = 1; d < 64; d <<= 1) m = fmaxf(m, __shfl_xor(m, d, 64));
    float s = 0.f;
    for (int j = 0; j < cnt; ++j) s += loc[j].y * expf(loc[j].x - m);
#pragma unroll
    for (int d = 1; d < 64; d <<= 1) s += __shfl_xor(s, d, 64);
    if (lane == 0) nll[row] = -(tgtlog[row] - m - logf(s));
}

__global__ __launch_bounds__(256) void loss_kernel(const float* __restrict__ nll,
                                                   float* __restrict__ out) {
    __shared__ float red[256];
    int tid = threadIdx.x;
    float s = 0.f;
    for (int i = tid; i < TT * BB; i += 256) s += nll[i];
    red[tid] = s; __syncthreads();
    for (int st = 128; st > 0; st >>= 1) { if (tid < st) red[tid] += red[tid + st]; __syncthreads(); }
    if (tid == 0) out[0] = red[0] / (float)BB;
}

extern "C" void kernel_launch(void* const* d_in, const int* in_sizes, int n_in,
                              void* d_out, int out_size, void* d_ws, size_t ws_size,
                              hipStream_t stream) {
    const int*   x   = (const int*)d_in[0];
    const int*   y   = (const int*)d_in[1];
    const float* emb = (const float*)d_in[2];
    const float* W0  = (const float*)d_in[3];
    const float* b0  = (const float*)d_in[4];
    const float* W1  = (const float*)d_in[5];
    const float* b1  = (const float*)d_in[6];
    const float* sw  = (const float*)d_in[7];
    const float* sb  = (const float*)d_in[8];
    float* out = (float*)d_out;

    // ---- workspace layout ----
    char* p = (char*)d_ws;
    unsigned short* A0   = (unsigned short*)p; p += (size_t)TT * BB * KT * 2;   // 13,762,560
    unsigned short* A1   = (unsigned short*)p; p += (size_t)2 * BB * KT * 2;    //    786,432
    unsigned short* outs = (unsigned short*)p; p += (size_t)MPAD * KLP * 2;     //  6,930,432 (rows 2240..2303 stay zero)
    float* c0 = (float*)p; p += (size_t)BB * HID * 4;
    float* c1 = (float*)p; p += (size_t)BB * HID * 4;
    size_t zero_bytes = (size_t)(p - (char*)d_ws);
    unsigned short* WbT0 = (unsigned short*)p; p += (size_t)6000 * KT * 2;      // 36,864,000
    unsigned short* WbT1 = (unsigned short*)p; p += (size_t)6000 * KT * 2;      // 36,864,000
    unsigned short* swT  = (unsigned short*)p; p += (size_t)VOCAB * KLP * 2;    // 30,080,000
    float2* partials = (float2*)p; p += (size_t)TT * BB * NBLK * 8;             //  2,831,360
    float* tgtlog = (float*)p; p += (size_t)TT * BB * 4;
    float* nll    = (float*)p;

    hipMemsetAsync(d_ws, 0, zero_bytes, stream);

    dim3 cblk(32, 8);
    convT<<<dim3(188, 96), cblk, 0, stream>>>(W0, WbT0, 3000, 6000, KT);
    convT<<<dim3(188, 96), cblk, 0, stream>>>(W1, WbT1, 3000, 6000, KT);
    convT<<<dim3(313, 47), cblk, 0, stream>>>(sw, swT, HID, VOCAB, KLP);

    embed_kernel<<<TT * BB, 256, 0, stream>>>(x, emb, A0);

    // software pipeline: launch k runs layer0[k] (blocks 0..93) and layer1[k-1]
    // (blocks 94..187) concurrently. 36 launches instead of 70, 188 CUs busy.
    for (int k = 0; k <= TT; ++k) {
        const unsigned short* A0t = (k < TT) ? A0 + (size_t)k * BB * KT : nullptr;
        unsigned short* d1_0 = A1 + (size_t)(k & 1) * BB * KT;
        unsigned short* d2_0 = (k < TT - 1) ? (A0 + (size_t)(k + 1) * BB * KT + EMB) : nullptr;

        const unsigned short* A1t = (k >= 1) ? A1 + (size_t)((k - 1) & 1) * BB * KT : nullptr;
        unsigned short* d1_1 = A1 + (size_t)(k & 1) * BB * KT + HID;
        unsigned short* d2_1 = (k >= 1) ? outs + (size_t)(k - 1) * BB * KLP : nullptr;

        lstm_pair<<<188, 1024, 0, stream>>>(A0t, WbT0, b0, c0, d1_0, KT, d2_0, KT,
                                            A1t, WbT1, b1, c1, d1_1, KT, d2_1, KLP);
    }

    logits_fold<<<dim3(79, 18), 256, 0, stream>>>(outs, swT, sb, y, partials, tgtlog);
    nll_reduce<<<TT * BB, 64, 0, stream>>>(partials, tgtlog, nll);
    loss_kernel<<<1, 256, 0, stream>>>(nll, out);
}

// Round 4
// 1254.801 us; speedup vs baseline: 1.8944x; 1.0983x over previous
//
#include <hip/hip_runtime.h>
#include <math.h>

#define TT 35
#define BB 64
#define EMB 1500
#define HID 1500
#define VOCAB 10000
#define KT 3072          // EMB+HID padded to x128 (4 k-groups x 24 chunks x 32)
#define KG 768           // K per k-group
#define NCH 24           // chunks of 32 per k-group
#define KLP 1504         // HID padded to x32 (logits K)
#define NBLK 158         // vocab 64-col blocks (79 tiles x 2 halves)
#define MROWS 2240       // T*B rows
#define MPAD 2304        // padded to 18*128
#define LBLK 94          // column-blocks per LSTM layer
#define FORGET_BIAS 1.0f

typedef __bf16 bf16x8 __attribute__((ext_vector_type(8)));
typedef float f32x4 __attribute__((ext_vector_type(4)));

__device__ __forceinline__ unsigned short f2bf(float f) {
    unsigned int u = __builtin_bit_cast(unsigned int, f);
    u += 0x7fffu + ((u >> 16) & 1u);           // RNE
    return (unsigned short)(u >> 16);
}
__device__ __forceinline__ float sigmoidf_(float x) { return 1.0f / (1.0f + expf(-x)); }

#define GLOAD_LDS16(gp, lp) __builtin_amdgcn_global_load_lds( \
    (const __attribute__((address_space(1))) void*)(gp),      \
    (__attribute__((address_space(3))) void*)(lp), 16, 0, 0)

// ---- W (K x N fp32) -> WT (N x KP bf16), zero-fill k in [K,KP) ----
__global__ __launch_bounds__(256) void convT(const float* __restrict__ W,
                                             unsigned short* __restrict__ WT,
                                             int K, int N, int KP) {
    __shared__ float tile[32][33];
    int tx = threadIdx.x, ty = threadIdx.y;    // 32 x 8
    int n0 = blockIdx.x * 32, k0 = blockIdx.y * 32;
#pragma unroll
    for (int i = 0; i < 4; ++i) {
        int k = k0 + ty + 8 * i, n = n0 + tx;
        tile[ty + 8 * i][tx] = (k < K && n < N) ? W[(size_t)k * N + n] : 0.f;
    }
    __syncthreads();
#pragma unroll
    for (int i = 0; i < 4; ++i) {
        int n = n0 + ty + 8 * i, k = k0 + tx;
        if (n < N) WT[(size_t)n * KP + k] = f2bf(tile[tx][ty + 8 * i]);
    }
}

// ---- embedding gather -> bf16 into per-step A0 buffers (cols 0..1499) ----
__global__ __launch_bounds__(256) void embed_kernel(const int* __restrict__ x,
                                                    const float* __restrict__ emb,
                                                    unsigned short* __restrict__ A0) {
    int tok = blockIdx.x;                       // t*BB + b (t-major)
    int v = x[tok];
    const float* src = emb + (size_t)v * EMB;
    unsigned short* dst = A0 + (size_t)tok * KT;
    for (int i = threadIdx.x; i < EMB; i += 256) dst[i] = f2bf(src[i]);
}

// ---- fused LSTM pair step: layer0[k] (blocks 0..93) || layer1[k-1] (94..187).
// Round-4 change: 4-buffer depth-3 global_load_lds pipeline with counted vmcnt
// (T3+T4). One raw s_barrier per chunk, NO vmcnt(0) drain in the loop — stages
// stay in flight across barriers. LDS = 4 x 32KB = 128KB; epilogue overlays it.
// Hazards: buf[(c+3)&3] was last read at iter c-1; those ds_reads completed
// before each wave's MFMAs (lgkmcnt) and hence before barrier(c); stage(c+3)
// is issued after barrier(c). Tail iters issue dummy re-stages so vmcnt(4)
// stays exact; full drain before the epilogue reduction overlay.
__global__ __launch_bounds__(1024) void lstm_pair(
        const unsigned short* __restrict__ A_0, const unsigned short* __restrict__ WT_0,
        const float* __restrict__ bias_0, float* __restrict__ cst_0,
        unsigned short* __restrict__ d1_0, int s1_0, unsigned short* __restrict__ d2_0, int s2_0,
        const unsigned short* __restrict__ A_1, const unsigned short* __restrict__ WT_1,
        const float* __restrict__ bias_1, float* __restrict__ cst_1,
        unsigned short* __restrict__ d1_1, int s1_1, unsigned short* __restrict__ d2_1, int s2_1) {
    __shared__ __align__(16) unsigned char smem[131072];

    const unsigned short* A;  const unsigned short* WT;
    const float* bias;        float* cst;
    unsigned short* d1; int s1; unsigned short* d2; int s2;
    int nb;
    if (blockIdx.x < LBLK) {
        if (!A_0) return;
        A = A_0; WT = WT_0; bias = bias_0; cst = cst_0;
        d1 = d1_0; s1 = s1_0; d2 = d2_0; s2 = s2_0;
        nb = blockIdx.x;
    } else {
        if (!A_1) return;
        A = A_1; WT = WT_1; bias = bias_1; cst = cst_1;
        d1 = d1_1; s1 = s1_1; d2 = d2_1; s2 = s2_1;
        nb = blockIdx.x - LBLK;
    }

    int tid = threadIdx.x;
    int wv = tid >> 6, lane = tid & 63;
    int mt = wv & 3, kg = wv >> 2;
    int quad = lane >> 4, l16 = lane & 15;
    int col = nb * 16 + l16;

    int rr = lane >> 2, p = lane & 3;
    int sp = p ^ (rr & 3);                      // XOR swizzle on the GLOBAL side
    int kbase = kg * KG;
    int q0 = mt * 2, q1 = q0 + 1;
    const unsigned short* gp[2];
    int ldsoff[2];
#pragma unroll
    for (int ii = 0; ii < 2; ++ii) {
        int q = ii ? q1 : q0;
        if (q < 4) {                            // A rows 16q+rr
            gp[ii] = A + (size_t)(16 * q + rr) * KT + kbase + sp * 8;
        } else {                                // B: gate g=q-4, col index rr
            int g = q - 4;
            int ci = nb * 16 + rr; if (ci > HID - 1) ci = HID - 1;   // clamp pad cols
            gp[ii] = WT + (size_t)(g * HID + ci) * KT + kbase + sp * 8;
        }
        ldsoff[ii] = ((q >> 2) * 4 + kg) * 4096 + (q & 3) * 1024;    // + buf*32768
    }

    int swz = (quad ^ (l16 & 3)) * 16;
    int aoff = (0 * 4 + kg) * 4096 + (mt * 16 + l16) * 64 + swz;     // + buf*32768
    int boff = (1 * 4 + kg) * 4096 + l16 * 64 + swz;                 // + gate*1024 + buf*32768

    f32x4 acc0 = {0.f,0.f,0.f,0.f}, acc1 = acc0, acc2 = acc0, acc3 = acc0;

    // prologue: stage chunks 0..2 into bufs 0..2 (6 loads/wave in flight)
#pragma unroll
    for (int ci = 0; ci < 3; ++ci) {
        GLOAD_LDS16(gp[0] + ci * 32, smem + ci * 32768 + ldsoff[0]);
        GLOAD_LDS16(gp[1] + ci * 32, smem + ci * 32768 + ldsoff[1]);
    }

    for (int c = 0; c < NCH; ++c) {
        // my stage(c) landed; chunks c+1,c+2 (4 loads) stay in flight
        asm volatile("s_waitcnt vmcnt(4)" ::: "memory");
        __builtin_amdgcn_sched_barrier(0);
        __builtin_amdgcn_s_barrier();           // all waves' stage(c) visible
        // stage chunk c+3 into buf[(c+3)&3] (retired at iter c-1); dummy
        // re-stage of the last chunk past the end keeps vmcnt arithmetic exact
        int cs = (c + 3 < NCH) ? (c + 3) : (NCH - 1);
        int bs_ = (c + 3) & 3;
        GLOAD_LDS16(gp[0] + cs * 32, smem + bs_ * 32768 + ldsoff[0]);
        GLOAD_LDS16(gp[1] + cs * 32, smem + bs_ * 32768 + ldsoff[1]);
        const unsigned char* base = smem + (c & 3) * 32768;
        bf16x8 a  = *(const bf16x8*)(base + aoff);
        bf16x8 b0 = *(const bf16x8*)(base + boff);
        bf16x8 b1 = *(const bf16x8*)(base + boff + 1024);
        bf16x8 b2 = *(const bf16x8*)(base + boff + 2048);
        bf16x8 b3 = *(const bf16x8*)(base + boff + 3072);
        __builtin_amdgcn_s_setprio(1);
        acc0 = __builtin_amdgcn_mfma_f32_16x16x32_bf16(a, b0, acc0, 0, 0, 0);
        acc1 = __builtin_amdgcn_mfma_f32_16x16x32_bf16(a, b1, acc1, 0, 0, 0);
        acc2 = __builtin_amdgcn_mfma_f32_16x16x32_bf16(a, b2, acc2, 0, 0, 0);
        acc3 = __builtin_amdgcn_mfma_f32_16x16x32_bf16(a, b3, acc3, 0, 0, 0);
        __builtin_amdgcn_s_setprio(0);
    }
    // drain all in-flight stages before reusing smem for the reduction
    asm volatile("s_waitcnt vmcnt(0)" ::: "memory");
    __builtin_amdgcn_sched_barrier(0);
    __syncthreads();

    float* red = (float*)smem;                  // [12 waves][64 lanes][16]
    if (kg > 0) {
        int w = (kg - 1) * 4 + mt;
#pragma unroll
        for (int r = 0; r < 4; ++r) {
            red[(w * 64 + lane) * 16 + r]      = acc0[r];
            red[(w * 64 + lane) * 16 + 4 + r]  = acc1[r];
            red[(w * 64 + lane) * 16 + 8 + r]  = acc2[r];
            red[(w * 64 + lane) * 16 + 12 + r] = acc3[r];
        }
    }
    __syncthreads();
    if (kg == 0) {
#pragma unroll
        for (int k2 = 0; k2 < 3; ++k2) {
            int w = k2 * 4 + mt;
#pragma unroll
            for (int r = 0; r < 4; ++r) {
                acc0[r] += red[(w * 64 + lane) * 16 + r];
                acc1[r] += red[(w * 64 + lane) * 16 + 4 + r];
                acc2[r] += red[(w * 64 + lane) * 16 + 8 + r];
                acc3[r] += red[(w * 64 + lane) * 16 + 12 + r];
            }
        }
        if (col < HID) {
            float bi = bias[col], bj = bias[HID + col];
            float bf_ = bias[2 * HID + col], bo = bias[3 * HID + col];
#pragma unroll
            for (int r = 0; r < 4; ++r) {
                int row = mt * 16 + quad * 4 + r;
                float zi = acc0[r] + bi;
                float zj = acc1[r] + bj;
                float zf = acc2[r] + bf_;
                float zo = acc3[r] + bo;
                int ci = row * HID + col;
                float cn = cst[ci] * sigmoidf_(zf + FORGET_BIAS) + sigmoidf_(zi) * tanhf(zj);
                float hn = tanhf(cn) * sigmoidf_(zo);
                cst[ci] = cn;
                unsigned short hb = f2bf(hn);
                d1[(size_t)row * s1 + col] = hb;
                if (d2) d2[(size_t)row * s2 + col] = hb;
            }
        }
    }
}

// ---- logits + flash fold, m97-style tiled GEMM (proven round-3 version) ----
__global__ __launch_bounds__(256) void logits_fold(const unsigned short* __restrict__ A,   // MPAD x KLP
                                                   const unsigned short* __restrict__ WT,  // 10000 x KLP
                                                   const float* __restrict__ sb,
                                                   const int* __restrict__ y,
                                                   float2* __restrict__ partials,          // [2240][NBLK]
                                                   float* __restrict__ tgtlog) {           // [2240]
    __shared__ __align__(16) unsigned char smem[32768];   // [buf][A 8K | B 8K]

    const int NWG = 79 * 18;                    // 1422
    const int NX = 8;
    const int q = NWG / NX, r = NWG % NX;       // 177, 6
    int orig = blockIdx.x + 79 * blockIdx.y;
    int xcd = orig % NX, idx = orig / NX;
    int wgid = (xcd < r ? xcd * (q + 1) : r * (q + 1) + (xcd - r) * q) + idx;
    int bn = wgid % 79, mb = wgid / 79;
    int n0 = bn * 128;

    int tid = threadIdx.x;
    int wv = tid >> 6, lane = tid & 63;
    int wr = wv >> 1, wc = wv & 1;
    int quad = lane >> 4, l16 = lane & 15;

    int rr = lane >> 2;                         // row within 16
    int ks = (lane & 3) ^ (rr & 3);             // pre-swizzled k-seg on global side
    const unsigned short* gA[2]; const unsigned short* gB[2];
    int ldsA[2], ldsB[2];
#pragma unroll
    for (int i = 0; i < 2; ++i) {
        int r16 = wv * 2 + i;                   // 0..7
        int ra = mb * 128 + r16 * 16 + rr;      // A row (padded, < MPAD)
        gA[i] = A + (size_t)ra * KLP + ks * 8;
        ldsA[i] = r16 * 1024;
        int rb = n0 + r16 * 16 + rr;            // WT row
        if (rb > VOCAB - 1) rb = VOCAB - 1;     // clamp pad rows (masked later)
        gB[i] = WT + (size_t)rb * KLP + ks * 8;
        ldsB[i] = 8192 + r16 * 1024;
    }

    int sw16 = (quad ^ (l16 & 3)) * 16;
    int aoff[4], boff[4];
#pragma unroll
    for (int f = 0; f < 4; ++f) {
        aoff[f] = (wr * 64 + f * 16 + l16) * 64 + sw16;
        boff[f] = 8192 + (wc * 64 + f * 16 + l16) * 64 + sw16;
    }

    f32x4 acc[4][4];
#pragma unroll
    for (int i = 0; i < 4; ++i)
#pragma unroll
        for (int j = 0; j < 4; ++j) acc[i][j] = (f32x4){0.f, 0.f, 0.f, 0.f};

#pragma unroll
    for (int i = 0; i < 2; ++i) {
        GLOAD_LDS16(gA[i], smem + ldsA[i]);
        GLOAD_LDS16(gB[i], smem + ldsB[i]);
    }
    __syncthreads();

    for (int c = 0; c < KLP / 32; ++c) {
        int buf = c & 1;
        if (c + 1 < KLP / 32) {
            int ob = (buf ^ 1) * 16384;
#pragma unroll
            for (int i = 0; i < 2; ++i) {
                GLOAD_LDS16(gA[i] + (c + 1) * 32, smem + ob + ldsA[i]);
                GLOAD_LDS16(gB[i] + (c + 1) * 32, smem + ob + ldsB[i]);
            }
        }
        const unsigned char* base = smem + buf * 16384;
        bf16x8 a[4], b[4];
#pragma unroll
        for (int f = 0; f < 4; ++f) {
            a[f] = *(const bf16x8*)(base + aoff[f]);
            b[f] = *(const bf16x8*)(base + boff[f]);
        }
#pragma unroll
        for (int ar = 0; ar < 4; ++ar)
#pragma unroll
            for (int cb = 0; cb < 4; ++cb)
                acc[ar][cb] = __builtin_amdgcn_mfma_f32_16x16x32_bf16(a[ar], b[cb], acc[ar][cb], 0, 0, 0);
        __syncthreads();
    }

    int colv[4]; float bs[4];
#pragma unroll
    for (int cb = 0; cb < 4; ++cb) {
        int c = n0 + wc * 64 + cb * 16 + l16;
        colv[cb] = c;
        int cc = (c < VOCAB) ? c : (VOCAB - 1);
        bs[cb] = sb[cc];
    }
    int nb2 = bn * 2 + wc;
#pragma unroll
    for (int ar = 0; ar < 4; ++ar) {
#pragma unroll
        for (int r2 = 0; r2 < 4; ++r2) {
            float v0 = acc[ar][0][r2] + bs[0];
            float v1 = acc[ar][1][r2] + bs[1];
            float v2 = acc[ar][2][r2] + bs[2];
            float v3 = acc[ar][3][r2] + bs[3];
            if (colv[0] >= VOCAB) v0 = -1e30f;
            if (colv[1] >= VOCAB) v1 = -1e30f;
            if (colv[2] >= VOCAB) v2 = -1e30f;
            if (colv[3] >= VOCAB) v3 = -1e30f;
            int row = mb * 128 + wr * 64 + ar * 16 + quad * 4 + r2;
            int t = y[row < MROWS ? row : 0];
            float tv = -1e30f;
            if (colv[0] == t) tv = v0;
            if (colv[1] == t) tv = v1;
            if (colv[2] == t) tv = v2;
            if (colv[3] == t) tv = v3;
            float mx = fmaxf(fmaxf(v0, v1), fmaxf(v2, v3));
#pragma unroll
            for (int d = 1; d < 16; d <<= 1) mx = fmaxf(mx, __shfl_xor(mx, d, 64));
            float sum = expf(v0 - mx) + expf(v1 - mx) + expf(v2 - mx) + expf(v3 - mx);
#pragma unroll
            for (int d = 1; d < 16; d <<= 1) sum += __shfl_xor(sum, d, 64);
#pragma unroll
            for (int d = 1; d < 16; d <<= 1) tv = fmaxf(tv, __shfl_xor(tv, d, 64));
            if (l16 == 0 && row < MROWS) {
                partials[(size_t)row * NBLK + nb2] = make_float2(mx, sum);
                if (tv > -5e29f) tgtlog[row] = tv;
            }
        }
    }
}

// ---- combine per-block partials -> nll per row; one wave per row ----
__global__ __launch_bounds__(64) void nll_reduce(const float2* __restrict__ partials,
                                                 const float* __restrict__ tgtlog,
                                                 float* __restrict__ nll) {
    int row = blockIdx.x;
    int lane = threadIdx.x;
    float2 loc[3];
    int cnt = 0;
    float m = -1e30f;
    for (int i = lane; i < NBLK; i += 64) {
        float2 p = partials[(size_t)row * NBLK + i];
        loc[cnt++] = p;
        m = fmaxf(m, p.x);
    }
#pragma unroll
    for (int d = 1; d < 64; d <<= 1) m = fmaxf(m, __shfl_xor(m, d, 64));
    float s = 0.f;
    for (int j = 0; j < cnt; ++j) s += loc[j].y * expf(loc[j].x - m);
#pragma unroll
    for (int d = 1; d < 64; d <<= 1) s += __shfl_xor(s, d, 64);
    if (lane == 0) nll[row] = -(tgtlog[row] - m - logf(s));
}

__global__ __launch_bounds__(256) void loss_kernel(const float* __restrict__ nll,
                                                   float* __restrict__ out) {
    __shared__ float red[256];
    int tid = threadIdx.x;
    float s = 0.f;
    for (int i = tid; i < TT * BB; i += 256) s += nll[i];
    red[tid] = s; __syncthreads();
    for (int st = 128; st > 0; st >>= 1) { if (tid < st) red[tid] += red[tid + st]; __syncthreads(); }
    if (tid == 0) out[0] = red[0] / (float)BB;
}

extern "C" void kernel_launch(void* const* d_in, const int* in_sizes, int n_in,
                              void* d_out, int out_size, void* d_ws, size_t ws_size,
                              hipStream_t stream) {
    const int*   x   = (const int*)d_in[0];
    const int*   y   = (const int*)d_in[1];
    const float* emb = (const float*)d_in[2];
    const float* W0  = (const float*)d_in[3];
    const float* b0  = (const float*)d_in[4];
    const float* W1  = (const float*)d_in[5];
    const float* b1  = (const float*)d_in[6];
    const float* sw  = (const float*)d_in[7];
    const float* sb  = (const float*)d_in[8];
    float* out = (float*)d_out;

    // ---- workspace layout ----
    char* p = (char*)d_ws;
    unsigned short* A0   = (unsigned short*)p; p += (size_t)TT * BB * KT * 2;   // 13,762,560
    unsigned short* A1   = (unsigned short*)p; p += (size_t)2 * BB * KT * 2;    //    786,432
    unsigned short* outs = (unsigned short*)p; p += (size_t)MPAD * KLP * 2;     //  6,930,432 (rows 2240..2303 stay zero)
    float* c0 = (float*)p; p += (size_t)BB * HID * 4;
    float* c1 = (float*)p; p += (size_t)BB * HID * 4;
    size_t zero_bytes = (size_t)(p - (char*)d_ws);
    unsigned short* WbT0 = (unsigned short*)p; p += (size_t)6000 * KT * 2;      // 36,864,000
    unsigned short* WbT1 = (unsigned short*)p; p += (size_t)6000 * KT * 2;      // 36,864,000
    unsigned short* swT  = (unsigned short*)p; p += (size_t)VOCAB * KLP * 2;    // 30,080,000
    float2* partials = (float2*)p; p += (size_t)TT * BB * NBLK * 8;             //  2,831,360
    float* tgtlog = (float*)p; p += (size_t)TT * BB * 4;
    float* nll    = (float*)p;

    hipMemsetAsync(d_ws, 0, zero_bytes, stream);

    dim3 cblk(32, 8);
    convT<<<dim3(188, 96), cblk, 0, stream>>>(W0, WbT0, 3000, 6000, KT);
    convT<<<dim3(188, 96), cblk, 0, stream>>>(W1, WbT1, 3000, 6000, KT);
    convT<<<dim3(313, 47), cblk, 0, stream>>>(sw, swT, HID, VOCAB, KLP);

    embed_kernel<<<TT * BB, 256, 0, stream>>>(x, emb, A0);

    // software pipeline: launch k runs layer0[k] (blocks 0..93) and layer1[k-1]
    // (blocks 94..187) concurrently. 36 launches instead of 70, 188 CUs busy.
    for (int k = 0; k <= TT; ++k) {
        const unsigned short* A0t = (k < TT) ? A0 + (size_t)k * BB * KT : nullptr;
        unsigned short* d1_0 = A1 + (size_t)(k & 1) * BB * KT;
        unsigned short* d2_0 = (k < TT - 1) ? (A0 + (size_t)(k + 1) * BB * KT + EMB) : nullptr;

        const unsigned short* A1t = (k >= 1) ? A1 + (size_t)((k - 1) & 1) * BB * KT : nullptr;
        unsigned short* d1_1 = A1 + (size_t)(k & 1) * BB * KT + HID;
        unsigned short* d2_1 = (k >= 1) ? outs + (size_t)(k - 1) * BB * KLP : nullptr;

        lstm_pair<<<188, 1024, 0, stream>>>(A0t, WbT0, b0, c0, d1_0, KT, d2_0, KT,
                                            A1t, WbT1, b1, c1, d1_1, KT, d2_1, KLP);
    }

    logits_fold<<<dim3(79, 18), 256, 0, stream>>>(outs, swT, sb, y, partials, tgtlog);
    nll_reduce<<<TT * BB, 64, 0, stream>>>(partials, tgtlog, nll);
    loss_kernel<<<1, 256, 0, stream>>>(nll, out);
}